// Round 9
// baseline (78.232 us; speedup 1.0000x reference)
//
#include <hip/hip_runtime.h>

// NEmbedding: out[b,f,e] = relu( x*P[f,e] + R[f,e] + c * W[f,k,e] ),
// c = (hi_k - x)/(hi_k - lo_k),  P = sum_n g_n W_n,  R = bias - sum_n lo_n g_n W_n,
// k = largest n with bins[f,n] <= x (0 if none); hi of last bin = -1.0.
//
// R1-R4: load-before-store batching (106->64), nt-stores neutral, pipelining
// neutral, prep restructure (61.6). R5/R6: barrier-free wave-autonomous
// structure neutral (62.1). R7: f-sliced blocks + W in LDS: 59.4 (-2.7), but
// introduced 2048 x 64KB = 128MB of W staging re-reads (write churn evicts
// the slice from the XCD L2 between same-slice blocks; 256+128+16 MB @ 7TB/s
// = 57us matches observed nemb ~55us).
// R8: persistent blocks. Grid = 512 = 8 slices x 64 bands = exactly 2
//     blocks/CU (full residency, no tail). Each block stages its 64KB W-slice
//     ONCE and loops a contiguous 512-row band (16 iters). Staging traffic
//     128MB -> 32MB paid once at t=0. slice = blockIdx&7 keeps XCD affinity;
//     contiguous bands improve DRAM page locality. x loads nontemporal.

#define FDIM 64
#define NB   64
#define EDIM 32
#define FSL  8      // features per slice
#define WPAD 33     // padded W row (floats)
#define NBLK 512    // persistent grid: 8 slices x 64 row-bands
#define ROWS_PER_BLK 512
#define ITERS (ROWS_PER_BLK / 32)

typedef __attribute__((ext_vector_type(4))) float f32x4;

__global__ __launch_bounds__(256) void prep_kernel(
    const float* __restrict__ bins, const float* __restrict__ W,
    const float* __restrict__ bias,
    float* __restrict__ P, float* __restrict__ R)
{
    const int f = blockIdx.x;
    const int t = threadIdx.x;
    __shared__ float sg[NB];
    __shared__ float sb[NB];
    __shared__ float redP[8][EDIM];
    __shared__ float redQ[8][EDIM];

    if (t < NB) {
        float lo = bins[f * NB + t];
        float hi = (t < NB - 1) ? bins[f * NB + t + 1] : -1.0f;
        sg[t] = 1.0f / (hi - lo);
        sb[t] = lo;
    }
    __syncthreads();

    const int e  = t & (EDIM - 1);
    const int ch = t >> 5;                    // 0..7, each owns 8 n's
    float p = 0.0f, q = 0.0f;
    const float* Wf = W + (size_t)f * NB * EDIM + e;
    #pragma unroll
    for (int i = 0; i < 8; ++i) {
        int n = ch * 8 + i;
        float w = Wf[n * EDIM];
        p = fmaf(sg[n], w, p);
        q = fmaf(sb[n] * sg[n], w, q);
    }
    redP[ch][e] = p;
    redQ[ch][e] = q;
    __syncthreads();

    if (t < EDIM) {
        float P_ = 0.0f, Q_ = 0.0f;
        #pragma unroll
        for (int c = 0; c < 8; ++c) { P_ += redP[c][t]; Q_ += redQ[c][t]; }
        P[f * EDIM + t] = P_;
        R[f * EDIM + t] = bias[f * EDIM + t] - Q_;
    }
}

__global__ __launch_bounds__(256) void nemb_kernel(
    const float* __restrict__ x, const float* __restrict__ bins,
    const float* __restrict__ W,
    const float* __restrict__ P, const float* __restrict__ R,
    float* __restrict__ out)
{
    __shared__ float sW[FSL * NB * WPAD];     // 67.6 KB, padded rows
    __shared__ float sBins[FSL * 65];         // 65th = -1.0 sentinel
    __shared__ float pX[4][64];               // per-wave patches [w][row*8+f]
    __shared__ float pC[4][64];
    __shared__ int   pK[4][64];

    const int t     = threadIdx.x;
    const int slice = blockIdx.x & 7;         // -> XCD-affine under %8 dispatch
    const int band  = blockIdx.x >> 3;        // 0..63: contiguous row band
    const int f0    = slice * FSL;

    // ---- stage W slice (64 KB) into padded LDS — ONCE per block ----
    const float* Wg = W + (size_t)f0 * NB * EDIM;
    #pragma unroll
    for (int i = 0; i < 16; ++i) {
        int qi = i * 256 + t;                 // f32x4 index within slice
        f32x4 v = reinterpret_cast<const f32x4*>(Wg)[qi];
        int gi = qi * 4;
        int fl = gi >> 11;                    // 0..7
        int n  = (gi >> 5) & 63;
        int e0 = gi & 31;                     // multiple of 4
        *reinterpret_cast<f32x4*>(&sW[fl * (NB * WPAD) + n * WPAD + e0]) = v;
    }
    // ---- stage bins slice + sentinels ----
    if (t < 128) {
        f32x4 v = reinterpret_cast<const f32x4*>(bins + f0 * NB)[t];
        int gi = t * 4;
        int fl = gi >> 6, n = gi & 63;
        float* d = &sBins[fl * 65 + n];
        d[0] = v.x; d[1] = v.y; d[2] = v.z; d[3] = v.w;
    }
    if (t < FSL) sBins[t * 65 + 64] = -1.0f;
    __syncthreads();                          // the only block-wide sync

    // ---- wave-autonomous: wave w owns rows {rb..rb+7} per iteration ----
    const int w  = t >> 6;
    const int l  = t & 63;
    const int rs = l >> 3;                    // search: row-in-8
    const int fs = l & 7;                     // search: f-in-slice
    const int ft = l >> 3;                    // store: f-in-slice
    const int e0 = (l & 7) * 4;               // store: e-quad

    // hoisted P/R for the store mapping (fixed per lane)
    const f32x4 Pv = *reinterpret_cast<const f32x4*>(P + (f0 + ft) * EDIM + e0);
    const f32x4 Rv = *reinterpret_cast<const f32x4*>(R + (f0 + ft) * EDIM + e0);

    const long r00 = (long)band * ROWS_PER_BLK;

    #pragma unroll 2
    for (int it = 0; it < ITERS; ++it) {
        const long rb = r00 + it * 32 + w * 8;

        // search for (row rb+rs, feature f0+fs); 8-lane-contiguous x reads
        float xv = __builtin_nontemporal_load(&x[(rb + rs) * FDIM + f0 + fs]);
        const float* bl = &sBins[fs * 65];
        int k = (bl[32] <= xv) ? 32 : 0;
        if (bl[k + 16] <= xv) k += 16;
        if (bl[k +  8] <= xv) k +=  8;
        if (bl[k +  4] <= xv) k +=  4;
        if (bl[k +  2] <= xv) k +=  2;
        if (bl[k +  1] <= xv) k +=  1;
        float lo = bl[k];
        float hi = bl[k + 1];                 // k=63 -> sentinel -1.0
        float cv = (hi - xv) * __builtin_amdgcn_rcpf(hi - lo);

        pX[w][rs * 8 + fs] = xv;
        pC[w][rs * 8 + fs] = cv;
        pK[w][rs * 8 + fs] = k;
        // per-wave DS drain; patch is wave-private so no barrier needed
        asm volatile("s_waitcnt lgkmcnt(0)" ::: "memory");

        // 8 rows x 1KB fully coalesced stores; W from LDS only
        #pragma unroll
        for (int r = 0; r < 8; ++r) {
            float xr = pX[w][r * 8 + ft];     // 8-lane broadcast reads
            float cr = pC[w][r * 8 + ft];
            int   kr = pK[w][r * 8 + ft];
            f32x4 Wv = *reinterpret_cast<const f32x4*>(
                &sW[ft * (NB * WPAD) + kr * WPAD + e0]);
            f32x4 o;
            o.x = fmaxf(fmaf(cr, Wv.x, fmaf(xr, Pv.x, Rv.x)), 0.0f);
            o.y = fmaxf(fmaf(cr, Wv.y, fmaf(xr, Pv.y, Rv.y)), 0.0f);
            o.z = fmaxf(fmaf(cr, Wv.z, fmaf(xr, Pv.z, Rv.z)), 0.0f);
            o.w = fmaxf(fmaf(cr, Wv.w, fmaf(xr, Pv.w, Rv.w)), 0.0f);
            *reinterpret_cast<f32x4*>(
                out + (rb + r) * (FDIM * EDIM) + (f0 + ft) * EDIM + e0) = o;
        }
    }
}

extern "C" void kernel_launch(void* const* d_in, const int* in_sizes, int n_in,
                              void* d_out, int out_size, void* d_ws, size_t ws_size,
                              hipStream_t stream) {
    const float* x    = (const float*)d_in[0];   // (B, F)
    const float* bins = (const float*)d_in[1];   // (F, NB) sorted rows
    const float* W    = (const float*)d_in[2];   // (F, NB, E)
    const float* bias = (const float*)d_in[3];   // (F, E)
    float* out = (float*)d_out;

    // workspace layout: P (F*E) | R (F*E)  -> 16 KB total
    float* P = (float*)d_ws;
    float* R = P + FDIM * EDIM;

    prep_kernel<<<FDIM, 256, 0, stream>>>(bins, W, bias, P, R);
    nemb_kernel<<<NBLK, 256, 0, stream>>>(x, bins, W, P, R, out);
}

// Round 10
// 59.226 us; speedup vs baseline: 1.3209x; 1.3209x over previous
//
#include <hip/hip_runtime.h>

// NEmbedding: out[b,f,e] = relu( x*P[f,e] + R[f,e] + c * W[f,k,e] ),
// c = (hi_k - x)/(hi_k - lo_k),  P = sum_n g_n W_n,  R = bias - sum_n lo_n g_n W_n,
// k = largest n with bins[f,n] <= x (0 if none); hi of last bin = -1.0.
//
// R1-R6: batching (106->64); nt-store/pipeline/barrier theories dead (61.6-62.1).
// R7: f-sliced blocks, W in LDS: 59.4. R8: persistent + nt-x REGRESSED (78.2):
//     unique W = 512KB lives in L3 permanently -> staging re-reads were never
//     HBM; the regression is exposed latency at 2 blocks/CU (nt-x = forced
//     ~900cy HBM on the per-iteration serial chain ahead of a 6-dependent-
//     ds_read search ~720cy; 2 waves/SIMD can't hide it).
// R9: R7 base + cut the serial chain: (1) x prefetched one iteration ahead
//     (plain cached loads; first one issued before the staging barrier);
//     (2) 8-ary counting search: 7 independent reads (level 1, broadcast,
//     conflict-free) + 7 independent reads (level 2) + lo/hi = 3 dependent
//     LDS rounds (~360cy) instead of 7 (~840cy). Count formulation
//     k = #{n>=1: bins[n]<=x} is exactly the binary-search result.

#define FDIM 64
#define NB   64
#define EDIM 32
#define FSL  8      // features per slice
#define NRPB 256    // rows per block
#define WPAD 33     // padded W row (floats)
#define ITERS (NRPB / 32)

typedef __attribute__((ext_vector_type(4))) float f32x4;

__global__ __launch_bounds__(256) void prep_kernel(
    const float* __restrict__ bins, const float* __restrict__ W,
    const float* __restrict__ bias,
    float* __restrict__ P, float* __restrict__ R)
{
    const int f = blockIdx.x;
    const int t = threadIdx.x;
    __shared__ float sg[NB];
    __shared__ float sb[NB];
    __shared__ float redP[8][EDIM];
    __shared__ float redQ[8][EDIM];

    if (t < NB) {
        float lo = bins[f * NB + t];
        float hi = (t < NB - 1) ? bins[f * NB + t + 1] : -1.0f;
        sg[t] = 1.0f / (hi - lo);
        sb[t] = lo;
    }
    __syncthreads();

    const int e  = t & (EDIM - 1);
    const int ch = t >> 5;                    // 0..7, each owns 8 n's
    float p = 0.0f, q = 0.0f;
    const float* Wf = W + (size_t)f * NB * EDIM + e;
    #pragma unroll
    for (int i = 0; i < 8; ++i) {
        int n = ch * 8 + i;
        float w = Wf[n * EDIM];
        p = fmaf(sg[n], w, p);
        q = fmaf(sb[n] * sg[n], w, q);
    }
    redP[ch][e] = p;
    redQ[ch][e] = q;
    __syncthreads();

    if (t < EDIM) {
        float P_ = 0.0f, Q_ = 0.0f;
        #pragma unroll
        for (int c = 0; c < 8; ++c) { P_ += redP[c][t]; Q_ += redQ[c][t]; }
        P[f * EDIM + t] = P_;
        R[f * EDIM + t] = bias[f * EDIM + t] - Q_;
    }
}

__global__ __launch_bounds__(256) void nemb_kernel(
    const float* __restrict__ x, const float* __restrict__ bins,
    const float* __restrict__ W,
    const float* __restrict__ P, const float* __restrict__ R,
    float* __restrict__ out)
{
    __shared__ float sW[FSL * NB * WPAD];     // 67.6 KB, padded rows
    __shared__ float sBins[FSL * 65];         // 65th = -1.0 sentinel
    __shared__ float pX[4][64];               // per-wave patches [w][row*8+f]
    __shared__ float pC[4][64];
    __shared__ int   pK[4][64];

    const int t     = threadIdx.x;
    const int slice = blockIdx.x & 7;         // -> XCD-affine under %8 dispatch
    const int chunk = blockIdx.x >> 3;
    const int f0    = slice * FSL;

    const int w  = t >> 6;
    const int l  = t & 63;
    const int rs = l >> 3;                    // search: row-in-8
    const int fs = l & 7;                     // search: f-in-slice
    const int ft = l >> 3;                    // store: f-in-slice
    const int e0 = (l & 7) * 4;               // store: e-quad

    const long r00 = (long)chunk * NRPB;

    // issue first x load before staging: latency overlaps staging + barrier
    float x_cur = x[(r00 + w * 8 + rs) * FDIM + f0 + fs];

    // ---- stage W slice (64 KB) into padded LDS ----
    const float* Wg = W + (size_t)f0 * NB * EDIM;
    #pragma unroll
    for (int i = 0; i < 16; ++i) {
        int qi = i * 256 + t;                 // f32x4 index within slice
        f32x4 v = reinterpret_cast<const f32x4*>(Wg)[qi];
        int gi = qi * 4;
        int fl = gi >> 11;                    // 0..7
        int n  = (gi >> 5) & 63;
        int ee = gi & 31;                     // multiple of 4
        *reinterpret_cast<f32x4*>(&sW[fl * (NB * WPAD) + n * WPAD + ee]) = v;
    }
    // ---- stage bins slice + sentinels ----
    if (t < 128) {
        f32x4 v = reinterpret_cast<const f32x4*>(bins + f0 * NB)[t];
        int gi = t * 4;
        int fl = gi >> 6, n = gi & 63;
        float* d = &sBins[fl * 65 + n];
        d[0] = v.x; d[1] = v.y; d[2] = v.z; d[3] = v.w;
    }
    if (t < FSL) sBins[t * 65 + 64] = -1.0f;
    __syncthreads();                          // the only block-wide sync

    // hoisted P/R for the store mapping (fixed per lane)
    const f32x4 Pv = *reinterpret_cast<const f32x4*>(P + (f0 + ft) * EDIM + e0);
    const f32x4 Rv = *reinterpret_cast<const f32x4*>(R + (f0 + ft) * EDIM + e0);

    const float* bl = &sBins[fs * 65];

    #pragma unroll 2
    for (int it = 0; it < ITERS; ++it) {
        const long rb = r00 + it * 32 + w * 8;

        float xv = x_cur;
        if (it + 1 < ITERS)                   // prefetch next iteration's x
            x_cur = x[(rb + 32 + rs) * FDIM + f0 + fs];

        // ---- 8-ary counting search: 3 dependent LDS rounds ----
        // level 1: 7 independent broadcast reads
        int k = 0;
        k += (bl[ 8] <= xv) ? 8 : 0;
        k += (bl[16] <= xv) ? 8 : 0;
        k += (bl[24] <= xv) ? 8 : 0;
        k += (bl[32] <= xv) ? 8 : 0;
        k += (bl[40] <= xv) ? 8 : 0;
        k += (bl[48] <= xv) ? 8 : 0;
        k += (bl[56] <= xv) ? 8 : 0;
        // level 2: 7 independent reads within the block
        {
            const float* b2 = bl + k;
            int inner = 0;
            inner += (b2[1] <= xv) ? 1 : 0;
            inner += (b2[2] <= xv) ? 1 : 0;
            inner += (b2[3] <= xv) ? 1 : 0;
            inner += (b2[4] <= xv) ? 1 : 0;
            inner += (b2[5] <= xv) ? 1 : 0;
            inner += (b2[6] <= xv) ? 1 : 0;
            inner += (b2[7] <= xv) ? 1 : 0;
            k += inner;
        }
        float lo = bl[k];
        float hi = bl[k + 1];                 // k=63 -> sentinel -1.0
        float cv = (hi - xv) * __builtin_amdgcn_rcpf(hi - lo);

        pX[w][rs * 8 + fs] = xv;
        pC[w][rs * 8 + fs] = cv;
        pK[w][rs * 8 + fs] = k;
        // per-wave DS drain; patch is wave-private so no barrier needed
        asm volatile("s_waitcnt lgkmcnt(0)" ::: "memory");

        // 8 rows x 1KB fully coalesced stores; W from LDS only
        #pragma unroll
        for (int r = 0; r < 8; ++r) {
            float xr = pX[w][r * 8 + ft];     // 8-lane broadcast reads
            float cr = pC[w][r * 8 + ft];
            int   kr = pK[w][r * 8 + ft];
            f32x4 Wv = *reinterpret_cast<const f32x4*>(
                &sW[ft * (NB * WPAD) + kr * WPAD + e0]);
            f32x4 o;
            o.x = fmaxf(fmaf(cr, Wv.x, fmaf(xr, Pv.x, Rv.x)), 0.0f);
            o.y = fmaxf(fmaf(cr, Wv.y, fmaf(xr, Pv.y, Rv.y)), 0.0f);
            o.z = fmaxf(fmaf(cr, Wv.z, fmaf(xr, Pv.z, Rv.z)), 0.0f);
            o.w = fmaxf(fmaf(cr, Wv.w, fmaf(xr, Pv.w, Rv.w)), 0.0f);
            *reinterpret_cast<f32x4*>(
                out + (rb + r) * (FDIM * EDIM) + (f0 + ft) * EDIM + e0) = o;
        }
    }
}

extern "C" void kernel_launch(void* const* d_in, const int* in_sizes, int n_in,
                              void* d_out, int out_size, void* d_ws, size_t ws_size,
                              hipStream_t stream) {
    const float* x    = (const float*)d_in[0];   // (B, F)
    const float* bins = (const float*)d_in[1];   // (F, NB) sorted rows
    const float* W    = (const float*)d_in[2];   // (F, NB, E)
    const float* bias = (const float*)d_in[3];   // (F, E)
    float* out = (float*)d_out;

    // workspace layout: P (F*E) | R (F*E)  -> 16 KB total
    float* P = (float*)d_ws;
    float* R = P + FDIM * EDIM;

    const int B = in_sizes[0] / FDIM;            // 32768
    const int nchunks = B / NRPB;                // 128

    prep_kernel<<<FDIM, 256, 0, stream>>>(bins, W, bias, P, R);
    nemb_kernel<<<nchunks * 8, 256, 0, stream>>>(x, bins, W, P, R, out);
}

// Round 11
// 56.592 us; speedup vs baseline: 1.3824x; 1.0465x over previous
//
#include <hip/hip_runtime.h>

// NEmbedding: out[b,f,e] = relu( x*P[f,e] + R[f,e] + c * W[f,k,e] ),
// c = (hi_k - x)/(hi_k - lo_k),  P = sum_n g_n W_n,  R = bias - sum_n lo_n g_n W_n,
// k = largest n with bins[f,n] <= x (0 if none); hi of last bin = -1.0.
//
// R1-R6: batching (106->64); nt-store/pipeline/barrier theories dead.
// R7: f-sliced blocks, W in LDS: 59.4. R8: persistent+nt-x regressed (78.2).
// R9: x-prefetch + 8-ary search NEUTRAL (59.2) -> in-loop latency theory dead.
// R10: fuse prep into nemb. dur_us is the whole graph: prep launch + exec +
//      d_ws graph-edge + nemb launch was ~8-12us of fixed overhead that no
//      in-kernel change could touch — the same order as the residual over the
//      write floor. Each block now computes P/R for its own 8-feature slice
//      redundantly (~16K FMAs, hidden under W staging): g & lo*g from global
//      bins pre-barrier, P/R from sW post-barrier, then R9's loop unchanged.
//      Single kernel, no d_ws.

#define FDIM 64
#define NB   64
#define EDIM 32
#define FSL  8      // features per slice
#define NRPB 256    // rows per block
#define WPAD 33     // padded W row (floats)
#define ITERS (NRPB / 32)

typedef __attribute__((ext_vector_type(4))) float f32x4;

__global__ __launch_bounds__(256) void nemb_fused(
    const float* __restrict__ x, const float* __restrict__ bins,
    const float* __restrict__ W, const float* __restrict__ bias,
    float* __restrict__ out)
{
    __shared__ float sW[FSL * NB * WPAD];     // 66.0 KB, padded rows
    __shared__ float sBins[FSL * 65];         // 65th = -1.0 sentinel
    __shared__ float sg [FSL * NB];           // g[n]
    __shared__ float slg[FSL * NB];           // lo[n]*g[n]
    __shared__ float sP [FSL * EDIM];
    __shared__ float sR [FSL * EDIM];
    __shared__ float pX[4][64];               // per-wave patches [w][row*8+f]
    __shared__ float pC[4][64];
    __shared__ int   pK[4][64];

    const int t     = threadIdx.x;
    const int slice = blockIdx.x & 7;         // -> XCD-affine under %8 dispatch
    const int chunk = blockIdx.x >> 3;
    const int f0    = slice * FSL;

    const int w  = t >> 6;
    const int l  = t & 63;
    const int rs = l >> 3;                    // search: row-in-8
    const int fs = l & 7;                     // search: f-in-slice
    const int ft = l >> 3;                    // store: f-in-slice
    const int e0 = (l & 7) * 4;               // store: e-quad

    const long r00 = (long)chunk * NRPB;

    // early independent loads: first x tile, bias fragment (hide under staging)
    float x_cur = x[(r00 + w * 8 + rs) * FDIM + f0 + fs];
    float bias_v = bias[(f0 + (t >> 5)) * EDIM + (t & 31)];

    // ---- g and lo*g from GLOBAL bins (no LDS dependence, pre-barrier) ----
    {
        int idx = t * 2;                      // 2 consecutive (fl, n) pairs
        int fl  = idx >> 6;                   // 0..7
        int n   = idx & 63;                   // even
        const float* bg = bins + (size_t)(f0 + fl) * NB;
        float b0v = bg[n];
        float b1v = bg[n + 1];                // n+1 <= 63, same row
        float b2v = (n + 1 == 63) ? -1.0f : bg[n + 2];
        float g0 = 1.0f / (b1v - b0v);
        float g1 = 1.0f / (b2v - b1v);
        sg [fl * NB + n]     = g0;
        sg [fl * NB + n + 1] = g1;
        slg[fl * NB + n]     = b0v * g0;
        slg[fl * NB + n + 1] = b1v * g1;
    }

    // ---- stage W slice (64 KB) into padded LDS ----
    const float* Wg = W + (size_t)f0 * NB * EDIM;
    #pragma unroll
    for (int i = 0; i < 16; ++i) {
        int qi = i * 256 + t;                 // f32x4 index within slice
        f32x4 v = reinterpret_cast<const f32x4*>(Wg)[qi];
        int gi = qi * 4;
        int fl = gi >> 11;                    // 0..7
        int n  = (gi >> 5) & 63;
        int ee = gi & 31;                     // multiple of 4
        *reinterpret_cast<f32x4*>(&sW[fl * (NB * WPAD) + n * WPAD + ee]) = v;
    }
    // ---- stage bins slice + sentinels ----
    if (t < 128) {
        f32x4 v = reinterpret_cast<const f32x4*>(bins + (size_t)f0 * NB)[t];
        int gi = t * 4;
        int fl = gi >> 6, n = gi & 63;
        float* d = &sBins[fl * 65 + n];
        d[0] = v.x; d[1] = v.y; d[2] = v.z; d[3] = v.w;
    }
    if (t < FSL) sBins[t * 65 + 64] = -1.0f;
    __syncthreads();                          // sW, sBins, sg, slg valid

    // ---- per-slice P/R: thread (fl = t>>5, e = t&31) ----
    {
        const int fl = t >> 5;
        const int e  = t & 31;
        const float* wrow = &sW[fl * (NB * WPAD) + e];
        const float* gr   = &sg [fl * NB];
        const float* lgr  = &slg[fl * NB];
        float p = 0.0f, q = 0.0f;
        #pragma unroll
        for (int n = 0; n < NB; ++n) {
            float wv = wrow[n * WPAD];
            p = fmaf(gr[n],  wv, p);
            q = fmaf(lgr[n], wv, q);
        }
        sP[fl * EDIM + e] = p;
        sR[fl * EDIM + e] = bias_v - q;
    }
    __syncthreads();                          // sP, sR valid

    // hoisted P/R for the store mapping (fixed per lane)
    const f32x4 Pv = *reinterpret_cast<const f32x4*>(&sP[ft * EDIM + e0]);
    const f32x4 Rv = *reinterpret_cast<const f32x4*>(&sR[ft * EDIM + e0]);

    const float* bl = &sBins[fs * 65];

    #pragma unroll 2
    for (int it = 0; it < ITERS; ++it) {
        const long rb = r00 + it * 32 + w * 8;

        float xv = x_cur;
        if (it + 1 < ITERS)                   // prefetch next iteration's x
            x_cur = x[(rb + 32 + rs) * FDIM + f0 + fs];

        // ---- 8-ary counting search: 3 dependent LDS rounds ----
        int k = 0;
        k += (bl[ 8] <= xv) ? 8 : 0;
        k += (bl[16] <= xv) ? 8 : 0;
        k += (bl[24] <= xv) ? 8 : 0;
        k += (bl[32] <= xv) ? 8 : 0;
        k += (bl[40] <= xv) ? 8 : 0;
        k += (bl[48] <= xv) ? 8 : 0;
        k += (bl[56] <= xv) ? 8 : 0;
        {
            const float* b2 = bl + k;
            int inner = 0;
            inner += (b2[1] <= xv) ? 1 : 0;
            inner += (b2[2] <= xv) ? 1 : 0;
            inner += (b2[3] <= xv) ? 1 : 0;
            inner += (b2[4] <= xv) ? 1 : 0;
            inner += (b2[5] <= xv) ? 1 : 0;
            inner += (b2[6] <= xv) ? 1 : 0;
            inner += (b2[7] <= xv) ? 1 : 0;
            k += inner;
        }
        float lo = bl[k];
        float hi = bl[k + 1];                 // k=63 -> sentinel -1.0
        float cv = (hi - xv) * __builtin_amdgcn_rcpf(hi - lo);

        pX[w][rs * 8 + fs] = xv;
        pC[w][rs * 8 + fs] = cv;
        pK[w][rs * 8 + fs] = k;
        // per-wave DS drain; patch is wave-private so no barrier needed
        asm volatile("s_waitcnt lgkmcnt(0)" ::: "memory");

        // 8 rows x 1KB fully coalesced stores; W from LDS only
        #pragma unroll
        for (int r = 0; r < 8; ++r) {
            float xr = pX[w][r * 8 + ft];     // 8-lane broadcast reads
            float cr = pC[w][r * 8 + ft];
            int   kr = pK[w][r * 8 + ft];
            f32x4 Wv = *reinterpret_cast<const f32x4*>(
                &sW[ft * (NB * WPAD) + kr * WPAD + e0]);
            f32x4 o;
            o.x = fmaxf(fmaf(cr, Wv.x, fmaf(xr, Pv.x, Rv.x)), 0.0f);
            o.y = fmaxf(fmaf(cr, Wv.y, fmaf(xr, Pv.y, Rv.y)), 0.0f);
            o.z = fmaxf(fmaf(cr, Wv.z, fmaf(xr, Pv.z, Rv.z)), 0.0f);
            o.w = fmaxf(fmaf(cr, Wv.w, fmaf(xr, Pv.w, Rv.w)), 0.0f);
            *reinterpret_cast<f32x4*>(
                out + (rb + r) * (FDIM * EDIM) + (f0 + ft) * EDIM + e0) = o;
        }
    }
}

extern "C" void kernel_launch(void* const* d_in, const int* in_sizes, int n_in,
                              void* d_out, int out_size, void* d_ws, size_t ws_size,
                              hipStream_t stream) {
    const float* x    = (const float*)d_in[0];   // (B, F)
    const float* bins = (const float*)d_in[1];   // (F, NB) sorted rows
    const float* W    = (const float*)d_in[2];   // (F, NB, E)
    const float* bias = (const float*)d_in[3];   // (F, E)
    float* out = (float*)d_out;

    const int B = in_sizes[0] / FDIM;            // 32768
    const int nchunks = B / NRPB;                // 128

    nemb_fused<<<nchunks * 8, 256, 0, stream>>>(x, bins, W, bias, out);
}

// Round 12
// 56.390 us; speedup vs baseline: 1.3873x; 1.0036x over previous
//
#include <hip/hip_runtime.h>

// NEmbedding: out[b,f,e] = relu( x*P[f,e] + R[f,e] + c * W[f,k,e] ),
// c = (hi_k - x)/(hi_k - lo_k),  P = sum_n g_n W_n,  R = bias - sum_n lo_n g_n W_n,
// k = largest n with bins[f,n] <= x (0 if none); hi of last bin = -1.0.
//
// R1-R9: batching (106->64); store-flavor/vmcnt/barrier/gather/latency theories
// all dead (59-64 plateau). R10: single fused kernel (56.6, -2.6 = launch+edge).
// R11: LDS footprint + LDS-op-count attack. 77KB -> 38.9KB (4 blocks/CU = 16
//      waves, 2x TLP): sW stored as RNE bf16 (stride 34 bf16 = 17 dwords, odd
//      -> both bank parities), patches/sg/slg eliminated — the (row,f)->(f,e)
//      transpose is now 3 ds_bpermute per store-row (unroll-constant addr),
//      P/R computed from sBins + rcp. DS ops/iter ~55 -> ~40, and LDS-unit
//      serialization headroom 1.8x -> ~3x. bf16 W error <= ~0.002 relative
//      -> ~360 abs at out~1.8e5, threshold 3625.

#define FDIM 64
#define NB   64
#define EDIM 32
#define FSL  8      // features per slice
#define NRPB 256    // rows per block
#define ITERS (NRPB / 32)
#define SWSTR 34    // bf16 per n-row = 17 dwords (odd -> bank spread)

typedef __attribute__((ext_vector_type(4))) float f32x4;

static __device__ __forceinline__ unsigned bf16rne(float f) {
    unsigned u = __float_as_uint(f);
    return (u + 0x7FFFu + ((u >> 16) & 1u)) >> 16;
}

__global__ __launch_bounds__(256) void nemb_fused(
    const float* __restrict__ x, const float* __restrict__ bins,
    const float* __restrict__ W, const float* __restrict__ bias,
    float* __restrict__ out)
{
    __shared__ unsigned short sW16[FSL * NB * SWSTR];  // 34.0 KB bf16
    __shared__ float sBins[FSL * 65];                  // 65th = -1.0 sentinel
    __shared__ float sP[FSL * EDIM];
    __shared__ float sR[FSL * EDIM];

    const int t     = threadIdx.x;
    const int slice = blockIdx.x & 7;         // XCD-affine under %8 dispatch
    const int chunk = blockIdx.x >> 3;
    const int f0    = slice * FSL;

    const int w  = t >> 6;
    const int l  = t & 63;
    const int rs = l >> 3;                    // search: row-in-8
    const int fs = l & 7;                     // search: f-in-slice
    const int ft = l >> 3;                    // store: f-in-slice
    const int e0 = (l & 7) * 4;               // store: e-quad

    const long r00 = (long)chunk * NRPB;

    // early independent loads (hidden under staging)
    float x_cur  = x[(r00 + w * 8 + rs) * FDIM + f0 + fs];
    float bias_v = bias[(f0 + (t >> 5)) * EDIM + (t & 31)];

    // ---- stage W slice as bf16 into LDS ----
    const float* Wg = W + (size_t)f0 * NB * EDIM;
    unsigned* sWd = reinterpret_cast<unsigned*>(sW16);
    #pragma unroll
    for (int i = 0; i < 16; ++i) {
        int qi = i * 256 + t;                 // f32x4 index within slice
        f32x4 v = reinterpret_cast<const f32x4*>(Wg)[qi];
        int gi = qi * 4;
        int fl = gi >> 11;                    // 0..7
        int n  = (gi >> 5) & 63;
        int ee = gi & 31;                     // multiple of 4
        unsigned u0 = bf16rne(v.x) | (bf16rne(v.y) << 16);
        unsigned u1 = bf16rne(v.z) | (bf16rne(v.w) << 16);
        int d0 = 17 * (fl * 64 + n) + (ee >> 1);
        sWd[d0]     = u0;
        sWd[d0 + 1] = u1;
    }
    // ---- stage bins slice + sentinels ----
    if (t < 128) {
        f32x4 v = reinterpret_cast<const f32x4*>(bins + (size_t)f0 * NB)[t];
        int gi = t * 4;
        int fl = gi >> 6, n = gi & 63;
        float* d = &sBins[fl * 65 + n];
        d[0] = v.x; d[1] = v.y; d[2] = v.z; d[3] = v.w;
    }
    if (t < FSL) sBins[t * 65 + 64] = -1.0f;
    __syncthreads();

    // ---- per-slice P/R from sBins (rcp) + bf16 sW ----
    {
        const int fl = t >> 5;
        const int e  = t & 31;
        float p = 0.0f, q = 0.0f;
        #pragma unroll
        for (int n = 0; n < NB; ++n) {
            float lo = sBins[fl * 65 + n];
            float hi = sBins[fl * 65 + n + 1];
            float gv = __builtin_amdgcn_rcpf(hi - lo);
            float wv = __uint_as_float((unsigned)sW16[(fl * 64 + n) * SWSTR + e] << 16);
            p = fmaf(gv, wv, p);
            q = fmaf(lo * gv, wv, q);
        }
        sP[fl * EDIM + e] = p;
        sR[fl * EDIM + e] = bias_v - q;
    }
    __syncthreads();

    // hoisted P/R fragments (fixed per lane)
    const f32x4 Pv = *reinterpret_cast<const f32x4*>(&sP[ft * EDIM + e0]);
    const f32x4 Rv = *reinterpret_cast<const f32x4*>(&sR[ft * EDIM + e0]);

    const float* bl = &sBins[fs * 65];
    const int bp_base = (l >> 3) * 4;         // bpermute byte addr component

    #pragma unroll 2
    for (int it = 0; it < ITERS; ++it) {
        const long rb = r00 + it * 32 + w * 8;

        float xv = x_cur;
        if (it + 1 < ITERS)                   // prefetch next iteration's x
            x_cur = x[(rb + 32 + rs) * FDIM + f0 + fs];

        // ---- 8-ary counting search: 3 dependent LDS rounds ----
        int k = 0;
        k += (bl[ 8] <= xv) ? 8 : 0;
        k += (bl[16] <= xv) ? 8 : 0;
        k += (bl[24] <= xv) ? 8 : 0;
        k += (bl[32] <= xv) ? 8 : 0;
        k += (bl[40] <= xv) ? 8 : 0;
        k += (bl[48] <= xv) ? 8 : 0;
        k += (bl[56] <= xv) ? 8 : 0;
        {
            const float* b2 = bl + k;
            int inner = 0;
            inner += (b2[1] <= xv) ? 1 : 0;
            inner += (b2[2] <= xv) ? 1 : 0;
            inner += (b2[3] <= xv) ? 1 : 0;
            inner += (b2[4] <= xv) ? 1 : 0;
            inner += (b2[5] <= xv) ? 1 : 0;
            inner += (b2[6] <= xv) ? 1 : 0;
            inner += (b2[7] <= xv) ? 1 : 0;
            k += inner;
        }
        float lo = bl[k];
        float hi = bl[k + 1];                 // k=63 -> sentinel -1.0
        float cv = (hi - xv) * __builtin_amdgcn_rcpf(hi - lo);

        // ---- transpose via ds_bpermute (src = (l>>3) + r*8), store 8 rows ----
        #pragma unroll
        for (int r = 0; r < 8; ++r) {
            const int a = bp_base + r * 32;   // src_lane*4
            float xr = __uint_as_float((unsigned)
                __builtin_amdgcn_ds_bpermute(a, (int)__float_as_uint(xv)));
            float cr = __uint_as_float((unsigned)
                __builtin_amdgcn_ds_bpermute(a, (int)__float_as_uint(cv)));
            int   kr = __builtin_amdgcn_ds_bpermute(a, k);

            int d0 = 17 * (ft * 64 + kr) + ((l & 7) << 1);
            unsigned u0 = sWd[d0];
            unsigned u1 = sWd[d0 + 1];
            f32x4 Wv;
            Wv.x = __uint_as_float(u0 << 16);
            Wv.y = __uint_as_float(u0 & 0xFFFF0000u);
            Wv.z = __uint_as_float(u1 << 16);
            Wv.w = __uint_as_float(u1 & 0xFFFF0000u);

            f32x4 o;
            o.x = fmaxf(fmaf(cr, Wv.x, fmaf(xr, Pv.x, Rv.x)), 0.0f);
            o.y = fmaxf(fmaf(cr, Wv.y, fmaf(xr, Pv.y, Rv.y)), 0.0f);
            o.z = fmaxf(fmaf(cr, Wv.z, fmaf(xr, Pv.z, Rv.z)), 0.0f);
            o.w = fmaxf(fmaf(cr, Wv.w, fmaf(xr, Pv.w, Rv.w)), 0.0f);
            *reinterpret_cast<f32x4*>(
                out + (rb + r) * (FDIM * EDIM) + (f0 + ft) * EDIM + e0) = o;
        }
    }
}

extern "C" void kernel_launch(void* const* d_in, const int* in_sizes, int n_in,
                              void* d_out, int out_size, void* d_ws, size_t ws_size,
                              hipStream_t stream) {
    const float* x    = (const float*)d_in[0];   // (B, F)
    const float* bins = (const float*)d_in[1];   // (F, NB) sorted rows
    const float* W    = (const float*)d_in[2];   // (F, NB, E)
    const float* bias = (const float*)d_in[3];   // (F, E)
    float* out = (float*)d_out;

    const int B = in_sizes[0] / FDIM;            // 32768
    const int nchunks = B / NRPB;                // 128

    nemb_fused<<<nchunks * 8, 256, 0, stream>>>(x, bins, W, bias, out);
}